// Round 11
// baseline (1319.884 us; speedup 1.0000x reference)
//
#include <hip/hip_runtime.h>
#include <hip/hip_bf16.h>
#include <float.h>

#define N_SRC 1024
#define N_TGT 100000
#define DIM   1024
#define KNN   4

// GEMM geometry: M = targets (128/block), N = sources (256/block), BK=64 fp8.
#define BM 128
#define BN 256
#define BK 64
#define NKT (DIM / BK)               // 16 K-tiles
#define NMB 782                      // target panels (782*128 = 100096)
#define N_TGT2 (NMB * BM)            // 100096 padded target rows
#define NSC (N_SRC / BN)             // 4 source chunks
#define NBLK (NMB * NSC)             // 3128
#define NSTRIP NMB                   // one 128-row strip per panel
#define NCAND (NSTRIP * KNN)         // 3128 candidates per source row
#define RERANK 32                    // widened for fp8 selection noise

#define SRC_KT_B 65536ull                              // src ws bytes per kt-plane
#define TGT_KT_B ((unsigned long long)N_TGT2 * 64ull)  // tgt ws bytes per kt-plane

#define SCALE1 0x7f7f7f7f            // e8m0 exponent 127 = 1.0 in every byte

typedef __attribute__((ext_vector_type(4)))  float f32x4;
typedef __attribute__((ext_vector_type(16))) float f32x16;
typedef __attribute__((ext_vector_type(4)))  unsigned int u32x4;
typedef __attribute__((ext_vector_type(4)))  int i32x4;
typedef __attribute__((ext_vector_type(8)))  int i32x8;

__device__ __forceinline__ void gload16(const void* gp, void* lp) {
    __builtin_amdgcn_global_load_lds(
        (const __attribute__((address_space(1))) void*)gp,
        (__attribute__((address_space(3))) void*)lp, 16, 0, 0);
}

// pack 4 f32 -> 4 fp8 e4m3 (RNE, OCP on gfx950) in one dword, k-order x..w
__device__ __forceinline__ unsigned int pk_fp8x4(float4 v) {
    int d = __builtin_amdgcn_cvt_pk_fp8_f32(v.x, v.y, 0, false);  // bytes 0,1
    d     = __builtin_amdgcn_cvt_pk_fp8_f32(v.z, v.w, d, true);   // bytes 2,3
    return (unsigned int)d;
}

// sorted-desc compare-exchange: (v1,i1) keeps the greater (tie -> lower idx)
__device__ __forceinline__ void ce_desc(float& v1, int& i1, float& v2, int& i2)
{
    bool sw = (v2 > v1) || (v2 == v1 && i2 < i1);
    float tv = sw ? v2 : v1; float uv = sw ? v1 : v2;
    int   ti = sw ? i2 : i1; int   ui = sw ? i1 : i2;
    v1 = tv; i1 = ti; v2 = uv; i2 = ui;
}

// ---------------------------------------------------------------------------
// Kernel 1: sources f32 -> fp8 ws, layout [kt16][1024 rows][4 pos x 16B].
// LINEAR k within each row's 64 B; 16B chunk c (k = c*16..c*16+15) stored at
// position c ^ ((row>>1)&3) (XOR swizzle; b128 frag reads are 2-way = free).
// ---------------------------------------------------------------------------
__global__ __launch_bounds__(256) void convert_src_kernel(
    const float* __restrict__ src, unsigned int* __restrict__ srcws)
{
    int gid = blockIdx.x * 256 + threadIdx.x;   // 16B position id; 65536 total
    int kt  = gid >> 12;                        // 0..15
    int rem = gid & 4095;
    int row = rem >> 2;
    int pos = rem & 3;
    int c   = pos ^ ((row >> 1) & 3);
    const float4* p = (const float4*)(src + (size_t)row * DIM + kt * BK + c * 16);
    u32x4 o = { pk_fp8x4(p[0]), pk_fp8x4(p[1]), pk_fp8x4(p[2]), pk_fp8x4(p[3]) };
    ((u32x4*)srcws)[gid] = o;
}

// ---------------------------------------------------------------------------
// Kernel 1b: targets f32 -> fp8 ws, same linear-k swizzled layout
// [kt16][N_TGT2 rows][4 x 16B], PLUS exact f32 inverse norms.
// ---------------------------------------------------------------------------
__global__ __launch_bounds__(256) void prep_tgt_kernel(
    const float* __restrict__ tgt, unsigned int* __restrict__ tgtbf,
    float* __restrict__ invnw)
{
    __shared__ float pn[16][17];
    const int t  = threadIdx.x;
    const int li = t & 15;
    const int kt = t >> 4;
    const int row = blockIdx.x * 16 + li;
    const bool valid = row < N_TGT;

    float4 v[16];
    if (valid) {
        const float4* p = (const float4*)(tgt + (size_t)row * DIM + kt * BK);
        #pragma unroll
        for (int i = 0; i < 16; ++i) v[i] = p[i];
    } else {
        #pragma unroll
        for (int i = 0; i < 16; ++i) v[i] = make_float4(0.f, 0.f, 0.f, 0.f);
    }
    float nsq = 0.f;
    #pragma unroll
    for (int i = 0; i < 16; ++i)
        nsq += v[i].x * v[i].x + v[i].y * v[i].y
             + v[i].z * v[i].z + v[i].w * v[i].w;

    u32x4* o = (u32x4*)((char*)tgtbf + (size_t)kt * TGT_KT_B
                        + (size_t)row * 64);
    const int f = (row >> 1) & 3;
    #pragma unroll
    for (int c = 0; c < 4; ++c) {
        o[c ^ f] = (u32x4){ pk_fp8x4(v[4 * c + 0]), pk_fp8x4(v[4 * c + 1]),
                            pk_fp8x4(v[4 * c + 2]), pk_fp8x4(v[4 * c + 3]) };
    }

    pn[li][kt] = nsq;
    __syncthreads();
    if (t < 16) {
        float s = 0.f;
        #pragma unroll
        for (int k = 0; k < 16; ++k) s += pn[t][k];
        int r2 = blockIdx.x * 16 + t;
        invnw[r2] = (r2 < N_TGT) ? 1.0f / sqrtf(s) : -1.0f;
    }
}

// ---------------------------------------------------------------------------
// Kernel 2: block-scaled fp8 MFMA GEMM (mfma_scale_f32_32x32x64_f8f6f4 with
// unit e8m0 scales -> bit-identical products to plain fp8, ~2x matrix rate).
// 128x256 tile, BK=64, 8 waves (wave 64x64 = 2x2 of 32x32), 48.5 KB LDS
// double-buffer, 2 blocks/CU, r9's minimal loop (schedule grafts proven null).
// A-frag: row = lane&31, k = (lane>>5)*32 + byte. C/D: col = lane&31,
// row = (reg&3) + 8*(reg>>2) + 4*(lane>>5)  [HW-verified, shape-determined].
// ---------------------------------------------------------------------------
__global__ __launch_bounds__(512, 4) void gemm_topk_fp8_kernel(
    const void* __restrict__ tgtbf, const void* __restrict__ srcbf,
    const float* __restrict__ invnw,
    float* __restrict__ cand_val, int* __restrict__ cand_idx)
{
    __shared__ __align__(16) unsigned char As[2][BM][BK];    // 16 KB
    __shared__ __align__(16) unsigned char Bs[2][BN][BK];    // 32 KB
    __shared__ float invn_sh[BM];                            // 0.5 KB

    // bijective XCD swizzle (3128 = 8*391): consecutive logicals on one XCD
    // share a target panel (4 source chunks) -> panel HBM-read once.
    const int b = blockIdx.x;
    const int logical = (b & 7) * (NBLK / 8) + (b >> 3);
    const int mblk = logical >> 2;          // 0..781
    const int schk = logical & 3;           // 0..3
    const int m0 = mblk * BM;
    const int c0 = schk * BN;

    const int t = threadIdx.x;
    const int lane = t & 63;
    const int w = t >> 6;                   // 8 waves
    const int wm = w >> 2, wn = w & 3;      // 2M x 4N, per-wave 64x64
    const int l31 = lane & 31;
    const int h = lane >> 5;                // k-half owner (0: k<32, 1: k>=32)

    const char* tb_ = (const char*)tgtbf;
    const char* sb_ = (const char*)srcbf;

    f32x16 acc[2][2];
    #pragma unroll
    for (int i = 0; i < 2; ++i)
        #pragma unroll
        for (int j = 0; j < 2; ++j)
            #pragma unroll
            for (int r = 0; r < 16; ++r) acc[i][j][r] = 0.f;

    unsigned char *Ac = &As[0][0][0], *An = &As[1][0][0];
    unsigned char *Bc = &Bs[0][0][0], *Bn = &Bs[1][0][0];

    // stage: A tile 8KB = 1 gload/thread, B tile 16KB = 2 gloads/thread.
    #define STAGE(Ab_, Bb_, kt_) do {                                         \
        const char* ga_ = tb_ + (size_t)(kt_) * TGT_KT_B + (size_t)m0 * 64    \
                          + (size_t)t * 16;                                   \
        gload16(ga_, (Ab_) + t * 16);                                         \
        const char* gb_ = sb_ + (size_t)(kt_) * SRC_KT_B + (size_t)c0 * 64    \
                          + (size_t)t * 16;                                   \
        gload16(gb_,        (Bb_) + t * 16);                                  \
        gload16(gb_ + 8192, (Bb_) + 8192 + t * 16);                           \
    } while (0)

    // frag read: lane needs k-bytes h*32..h*32+31 of its row = content chunks
    // {2h, 2h+1}, each stored at chunk ^ ((row>>1)&3). Rows are base + l31
    // with base % 32 == 0, so the swizzle term depends only on the lane.
    const int sw8 = (l31 >> 1) & 3;
    const int pA = ((2 * h + 0) ^ sw8) * 16;
    const int pB = ((2 * h + 1) ^ sw8) * 16;

    #define READ_FRAG(dst_, base_, rowoff_) do {                              \
        i32x4 lo_ = *(const i32x4*)((base_) + (rowoff_) + pA);                \
        i32x4 hi_ = *(const i32x4*)((base_) + (rowoff_) + pB);                \
        dst_[0] = lo_[0]; dst_[1] = lo_[1]; dst_[2] = lo_[2]; dst_[3] = lo_[3];\
        dst_[4] = hi_[0]; dst_[5] = hi_[1]; dst_[6] = hi_[2]; dst_[7] = hi_[3];\
    } while (0)

    #define READ_AB do {                                                      \
        READ_FRAG(afr[0], Ac, (wm * 64 +  0 + l31) * BK);                     \
        READ_FRAG(afr[1], Ac, (wm * 64 + 32 + l31) * BK);                     \
        READ_FRAG(bfr[0], Bc, (wn * 64 +  0 + l31) * BK);                     \
        READ_FRAG(bfr[1], Bc, (wn * 64 + 32 + l31) * BK);                     \
    } while (0)

    #define DO_MFMA do {                                                      \
        _Pragma("unroll")                                                     \
        for (int mi = 0; mi < 2; ++mi)                                        \
            _Pragma("unroll")                                                 \
            for (int ni = 0; ni < 2; ++ni)                                    \
                acc[mi][ni] = __builtin_amdgcn_mfma_scale_f32_32x32x64_f8f6f4(\
                    afr[mi], bfr[ni], acc[mi][ni],                            \
                    0, 0, 0, SCALE1, 0, SCALE1);                              \
    } while (0)

    // ---- prologue: stage tile 0 (syncthreads drains vmcnt+lgkmcnt)
    STAGE(Ac, Bc, 0);
    __syncthreads();

    // ---- main loop: one barrier per K-tile (K=64)
    for (int kt = 0; kt < NKT; ++kt) {
        if (kt + 1 < NKT) STAGE(An, Bn, kt + 1);
        i32x8 afr[2], bfr[2];
        READ_AB;
        DO_MFMA;
        __syncthreads();
        unsigned char* tmp_;
        tmp_ = Ac; Ac = An; An = tmp_;
        tmp_ = Bc; Bc = Bn; Bn = tmp_;
    }
    #undef STAGE
    #undef READ_FRAG
    #undef READ_AB
    #undef DO_MFMA

    // ---- epilogue (scratch aliased onto As, dead now) ----------------------
    float* scv = (float*)&As[0][0][0];                   // 8 KB: 2*BN*KNN f32
    int*   sci = (int*)&As[1][0][0];                     // 8 KB

    if (t < BM) invn_sh[t] = invnw[m0 + t];
    __syncthreads();

    // lane's rows for acc[mi][*] reg r: local = mi*32 + (r&3) + 8*(r>>2) + 4*h
    float invr[2][16];
    #pragma unroll
    for (int mi = 0; mi < 2; ++mi)
        #pragma unroll
        for (int r = 0; r < 16; ++r)
            invr[mi][r] = invn_sh[wm * 64 + mi * 32 + (r & 3) + 8 * (r >> 2)
                                  + 4 * h];

    #pragma unroll
    for (int ni = 0; ni < 2; ++ni) {
        const int col = wn * 64 + ni * 32 + l31;         // 0..255
        float s[2][16];
        #pragma unroll
        for (int mi = 0; mi < 2; ++mi)
            #pragma unroll
            for (int r = 0; r < 16; ++r)
                s[mi][r] = (invr[mi][r] > 0.f) ? acc[mi][ni][r] * invr[mi][r]
                                               : -FLT_MAX;
        #pragma unroll
        for (int it = 0; it < KNN; ++it) {
            // local argmax over this lane's 32 rows; id = wave-local row [0,64)
            float bv = -FLT_MAX; int bid = 0;
            #pragma unroll
            for (int mi = 0; mi < 2; ++mi)
                #pragma unroll
                for (int r = 0; r < 16; ++r) {
                    int id = mi * 32 + (r & 3) + 8 * (r >> 2) + 4 * h;
                    if (s[mi][r] > bv) { bv = s[mi][r]; bid = id; }
                }
            // merge with the partner lane holding the same column
            {
                float ov = __shfl_xor(bv, 32);
                int   oi = __shfl_xor(bid, 32);
                if (ov > bv || (ov == bv && oi < bid)) { bv = ov; bid = oi; }
            }
            // invalidate winner (static indices only)
            const int hw  = (bid >> 2) & 1;
            const int miw = bid >> 5;
            const int rw  = (bid & 3) | (((bid >> 3) & 3) << 2);
            if (h == hw) {
                #pragma unroll
                for (int mi = 0; mi < 2; ++mi)
                    #pragma unroll
                    for (int r = 0; r < 16; ++r)
                        if (mi == miw && r == rw) s[mi][r] = -FLT_MAX;
            }
            if (h == 0) {
                int o = (wm * BN + col) * KNN + it;
                scv[o] = bv;
                sci[o] = m0 + wm * 64 + bid;             // global target row
            }
        }
    }
    __syncthreads();

    // merge the two wm halves: thread t<256 -> top-4 of 8 for column t
    if (t < BN) {
        float v4[4] = { -FLT_MAX, -FLT_MAX, -FLT_MAX, -FLT_MAX };
        int   i4[4] = { 0x7fffffff, 0x7fffffff, 0x7fffffff, 0x7fffffff };
        #pragma unroll
        for (int q = 0; q < 8; ++q) {
            int o = ((q >> 2) * BN + t) * KNN + (q & 3);
            float v = scv[o]; int ix = sci[o];
            if (v > v4[3] || (v == v4[3] && ix < i4[3])) {
                v4[3] = v; i4[3] = ix;
                ce_desc(v4[2], i4[2], v4[3], i4[3]);
                ce_desc(v4[1], i4[1], v4[2], i4[2]);
                ce_desc(v4[0], i4[0], v4[1], i4[1]);
            }
        }
        size_t o = ((size_t)(c0 + t) * NSTRIP + mblk) * KNN;
        #pragma unroll
        for (int it = 0; it < KNN; ++it) {
            cand_val[o + it] = v4[it];
            cand_idx[o + it] = i4[it];
        }
    }
}

// ---------------------------------------------------------------------------
// Kernel 3: per source row — candidate top-32, exact f32 rerank, top-4,
// gather + mean. One block (256 thr) per row.
// ---------------------------------------------------------------------------
__global__ __launch_bounds__(256) void merge_rerank_kernel(
    const float* __restrict__ src, const float* __restrict__ tgt,
    const float* __restrict__ cand_val, const int* __restrict__ cand_idx,
    float* __restrict__ out)
{
    __shared__ float sv[NCAND];          // 12.5 KB
    __shared__ float red_v[4];
    __shared__ int   red_p[4];
    __shared__ int   topi[RERANK];
    __shared__ float rsim[RERANK];
    __shared__ int   ridx[RERANK];
    __shared__ int   sel[KNN];

    const int row = blockIdx.x;
    const int t = threadIdx.x, lane = t & 63, w = t >> 6;
    const float* cv = cand_val + (size_t)row * NCAND;
    const int*   ci = cand_idx + (size_t)row * NCAND;

    for (int i = t; i < NCAND; i += 256) sv[i] = cv[i];
    __syncthreads();

    for (int it = 0; it < RERANK; ++it) {
        float bv = -FLT_MAX; int bp = 0;
        for (int i = t; i < NCAND; i += 256) {
            float v = sv[i];
            if (v > bv) { bv = v; bp = i; }
        }
        #pragma unroll
        for (int off = 1; off < 64; off <<= 1) {
            float ov = __shfl_xor(bv, off);
            int   op = __shfl_xor(bp, off);
            if (ov > bv || (ov == bv && op < bp)) { bv = ov; bp = op; }
        }
        if (lane == 0) { red_v[w] = bv; red_p[w] = bp; }
        __syncthreads();
        if (t == 0) {
            float Bv = red_v[0]; int Bp = red_p[0];
            for (int q = 1; q < 4; ++q)
                if (red_v[q] > Bv || (red_v[q] == Bv && red_p[q] < Bp)) {
                    Bv = red_v[q]; Bp = red_p[q];
                }
            topi[it] = ci[Bp];
            sv[Bp] = -FLT_MAX;
        }
        __syncthreads();
    }

    // exact f32 rerank: dot AND target norm from the same row read
    const float4* sp = (const float4*)(src + (size_t)row * DIM);
    #pragma unroll
    for (int q = 0; q < 8; ++q) {
        int cidx = topi[w + 4 * q];
        const float4* tp = (const float4*)(tgt + (size_t)cidx * DIM);
        float a = 0.f, nn = 0.f;
        #pragma unroll
        for (int p = 0; p < 4; ++p) {
            float4 x = sp[lane + 64 * p], y = tp[lane + 64 * p];
            a  = fmaf(x.x, y.x, a);  a  = fmaf(x.y, y.y, a);
            a  = fmaf(x.z, y.z, a);  a  = fmaf(x.w, y.w, a);
            nn = fmaf(y.x, y.x, nn); nn = fmaf(y.y, y.y, nn);
            nn = fmaf(y.z, y.z, nn); nn = fmaf(y.w, y.w, nn);
        }
        #pragma unroll
        for (int off = 1; off < 64; off <<= 1) {
            a  += __shfl_xor(a, off);
            nn += __shfl_xor(nn, off);
        }
        if (lane == 0) { rsim[w + 4 * q] = a / sqrtf(nn); ridx[w + 4 * q] = cidx; }
    }
    __syncthreads();

    if (w == 0) {
        float v = (lane < RERANK) ? rsim[lane] : -FLT_MAX;
        int  ix = (lane < RERANK) ? ridx[lane] : 0x7fffffff;
        #pragma unroll
        for (int it = 0; it < KNN; ++it) {
            float bv = v; int bix = ix;
            #pragma unroll
            for (int off = 1; off < 32; off <<= 1) {
                float ov = __shfl_xor(bv, off);
                int   oi = __shfl_xor(bix, off);
                if (ov > bv || (ov == bv && oi < bix)) { bv = ov; bix = oi; }
            }
            if (lane == 0) sel[it] = bix;
            if (ix == bix) v = -FLT_MAX;
        }
    }
    __syncthreads();

    const float4* g0 = (const float4*)(tgt + (size_t)sel[0] * DIM);
    const float4* g1 = (const float4*)(tgt + (size_t)sel[1] * DIM);
    const float4* g2 = (const float4*)(tgt + (size_t)sel[2] * DIM);
    const float4* g3 = (const float4*)(tgt + (size_t)sel[3] * DIM);
    float4* po = (float4*)(out + (size_t)row * DIM);
    float4 v0 = g0[t], v1 = g1[t], v2 = g2[t], v3 = g3[t];
    float4 rr;
    rr.x = (v0.x + v1.x + v2.x + v3.x) * 0.25f;
    rr.y = (v0.y + v1.y + v2.y + v3.y) * 0.25f;
    rr.z = (v0.z + v1.z + v2.z + v3.z) * 0.25f;
    rr.w = (v0.w + v1.w + v2.w + v3.w) * 0.25f;
    po[t] = rr;
}

// ---------------------------------------------------------------------------
extern "C" void kernel_launch(void* const* d_in, const int* in_sizes, int n_in,
                              void* d_out, int out_size, void* d_ws, size_t ws_size,
                              hipStream_t stream)
{
    const float* src = (const float*)d_in[0];
    const float* tgt = (const float*)d_in[1];
    float* out = (float*)d_out;

    const size_t SRCBF_B = 2097152;                       // 1 MB used, 2 MB reserved
    const size_t TGTBF_B = (size_t)N_TGT2 * 1024;         // ~102.5 MB (16 planes x 64B)
    const size_t INVN_B  = (size_t)N_TGT2 * 4;            // 0.4 MB
    const size_t CV_B    = (size_t)N_SRC * NCAND * 4;     // 12.8 MB

    char* p = (char*)d_ws;
    unsigned int* srcbf = (unsigned int*)p;
    unsigned int* tgtbf = (unsigned int*)(p + SRCBF_B);
    float* invnw    = (float*)(p + SRCBF_B + TGTBF_B);
    float* cand_val = (float*)(p + SRCBF_B + TGTBF_B + INVN_B);
    int*   cand_idx = (int*)(p + SRCBF_B + TGTBF_B + INVN_B + CV_B);

    convert_src_kernel<<<256, 256, 0, stream>>>(src, srcbf);
    prep_tgt_kernel<<<N_TGT2 / 16, 256, 0, stream>>>(tgt, tgtbf, invnw);
    gemm_topk_fp8_kernel<<<NBLK, 512, 0, stream>>>(tgtbf, srcbf, invnw,
                                                   cand_val, cand_idx);
    merge_rerank_kernel<<<N_SRC, 256, 0, stream>>>(src, tgt,
                                                   cand_val, cand_idx, out);
}

// Round 12
// 400.689 us; speedup vs baseline: 3.2940x; 3.2940x over previous
//
#include <hip/hip_runtime.h>
#include <hip/hip_bf16.h>
#include <float.h>

#define N_SRC 1024
#define N_TGT 100000
#define DIM   1024
#define KNN   4

// GEMM geometry: M = targets (128/block), N = sources (256/block), BK=64 (fp8).
#define BM 128
#define BN 256
#define BK 64
#define NKT (DIM / BK)               // 16 K-tiles
#define NMB 782                      // target panels (782*128 = 100096)
#define N_TGT2 (NMB * BM)            // 100096 padded target rows
#define NSC (N_SRC / BN)             // 4 source chunks
#define NBLK (NMB * NSC)             // 3128
#define NSTRIP NMB                   // one 128-row strip per panel
#define NCAND (NSTRIP * KNN)         // 3128 candidates per source row
#define RERANK 32                    // widened for fp8 selection noise

#define SRC_KT_B 65536ull                              // src ws bytes per kt-plane
#define TGT_KT_B ((unsigned long long)N_TGT2 * 64ull)  // tgt ws bytes per kt-plane

typedef __attribute__((ext_vector_type(4))) float f32x4;
typedef __attribute__((ext_vector_type(4))) unsigned int u32x4;
typedef __attribute__((ext_vector_type(2))) long long i64x2;

__device__ __forceinline__ void gload16(const void* gp, void* lp) {
    __builtin_amdgcn_global_load_lds(
        (const __attribute__((address_space(1))) void*)gp,
        (__attribute__((address_space(3))) void*)lp, 16, 0, 0);
}

// pack 4 f32 -> 4 fp8 e4m3 (RNE, OCP on gfx950) in one dword, k-order x0..x3
__device__ __forceinline__ unsigned int pk_fp8x4(float x0, float x1,
                                                 float x2, float x3) {
    int d = __builtin_amdgcn_cvt_pk_fp8_f32(x0, x1, 0, false);   // bytes 0,1
    d     = __builtin_amdgcn_cvt_pk_fp8_f32(x2, x3, d, true);    // bytes 2,3
    return (unsigned int)d;
}

// sorted-desc compare-exchange: (v1,i1) keeps the greater (tie -> lower idx)
__device__ __forceinline__ void ce_desc(float& v1, int& i1, float& v2, int& i2)
{
    bool sw = (v2 > v1) || (v2 == v1 && i2 < i1);
    float tv = sw ? v2 : v1; float uv = sw ? v1 : v2;
    int   ti = sw ? i2 : i1; int   ui = sw ? i1 : i2;
    v1 = tv; i1 = ti; v2 = uv; i2 = ui;
}

// ---------------------------------------------------------------------------
// Kernel 1: sources f32 -> fp8 ws, layout [kt16][1024 rows][4 pos x 16B].
// Position p of a row holds content chunk c = p ^ ((row>>1)&3):
// bytes 0..7  = fp8(k = kt*64 + c*8 + 0..7)         (kw0 half)
// bytes 8..15 = fp8(k = kt*64 + 32 + c*8 + 0..7)    (kw1 half)
// ---------------------------------------------------------------------------
__global__ __launch_bounds__(256) void convert_src_kernel(
    const float* __restrict__ src, unsigned int* __restrict__ srcws)
{
    int gid = blockIdx.x * 256 + threadIdx.x;   // 16B position id; 65536 total
    int kt  = gid >> 12;                        // 0..15
    int rem = gid & 4095;
    int row = rem >> 2;
    int pos = rem & 3;
    int c   = pos ^ ((row >> 1) & 3);
    const float4* p0 = (const float4*)(src + (size_t)row * DIM + kt * BK + c * 8);
    const float4* p1 = (const float4*)(src + (size_t)row * DIM + kt * BK + 32 + c * 8);
    float4 a0 = p0[0], a1 = p0[1], b0 = p1[0], b1 = p1[1];
    u32x4 o = { pk_fp8x4(a0.x, a0.y, a0.z, a0.w),
                pk_fp8x4(a1.x, a1.y, a1.z, a1.w),
                pk_fp8x4(b0.x, b0.y, b0.z, b0.w),
                pk_fp8x4(b1.x, b1.y, b1.z, b1.w) };
    ((u32x4*)srcws)[gid] = o;
}

// ---------------------------------------------------------------------------
// Kernel 1b: targets f32 -> fp8 ws, same layout [kt16][N_TGT2 rows][4 x 16B],
// PLUS exact f32 inverse norms. Thread t: row = blk*16 + (t&15), kt = t>>4.
// ---------------------------------------------------------------------------
__global__ __launch_bounds__(256) void prep_tgt_kernel(
    const float* __restrict__ tgt, unsigned int* __restrict__ tgtbf,
    float* __restrict__ invnw)
{
    __shared__ float pn[16][17];
    const int t  = threadIdx.x;
    const int li = t & 15;
    const int kt = t >> 4;
    const int row = blockIdx.x * 16 + li;
    const bool valid = row < N_TGT;

    float4 v[16];
    if (valid) {
        const float4* p = (const float4*)(tgt + (size_t)row * DIM + kt * BK);
        #pragma unroll
        for (int i = 0; i < 16; ++i) v[i] = p[i];
    } else {
        #pragma unroll
        for (int i = 0; i < 16; ++i) v[i] = make_float4(0.f, 0.f, 0.f, 0.f);
    }
    float nsq = 0.f;
    #pragma unroll
    for (int i = 0; i < 16; ++i)
        nsq += v[i].x * v[i].x + v[i].y * v[i].y
             + v[i].z * v[i].z + v[i].w * v[i].w;

    u32x4* o = (u32x4*)((char*)tgtbf + (size_t)kt * TGT_KT_B
                        + (size_t)row * 64);
    const int f = (row >> 1) & 3;
    #pragma unroll
    for (int c = 0; c < 4; ++c) {
        float4 a0 = v[2 * c], a1 = v[2 * c + 1];        // kw0: k = c*8..c*8+7
        float4 b0 = v[8 + 2 * c], b1 = v[8 + 2 * c + 1];// kw1: k = 32+c*8..+7
        o[c ^ f] = (u32x4){ pk_fp8x4(a0.x, a0.y, a0.z, a0.w),
                            pk_fp8x4(a1.x, a1.y, a1.z, a1.w),
                            pk_fp8x4(b0.x, b0.y, b0.z, b0.w),
                            pk_fp8x4(b1.x, b1.y, b1.z, b1.w) };
    }

    pn[li][kt] = nsq;
    __syncthreads();
    if (t < 16) {
        float s = 0.f;
        #pragma unroll
        for (int k = 0; k < 16; ++k) s += pn[t][k];
        int r2 = blockIdx.x * 16 + t;
        invnw[r2] = (r2 < N_TGT) ? 1.0f / sqrtf(s) : -1.0f;
    }
}

// ---------------------------------------------------------------------------
// Kernel 2: fp8 MFMA GEMM, 128x256 tile, BK=64, 8 waves (wave 64x64), r9's
// minimal 2-buffer loop. LDS cut to 48.5 KB by aliasing the epilogue scratch
// onto the dead A-buffers -> 3 blocks/CU (was 2). Per K-tile: {3
// global_load_lds (next tile) | 8 ds_read_b128 | 32 mfma_16x16x32_fp8_fp8 |
// __syncthreads()}.
// ---------------------------------------------------------------------------
__global__ __launch_bounds__(512, 4) void gemm_topk_fp8_kernel(
    const void* __restrict__ tgtbf, const void* __restrict__ srcbf,
    const float* __restrict__ invnw,
    float* __restrict__ cand_val, int* __restrict__ cand_idx)
{
    __shared__ __align__(16) unsigned char As[2][BM][BK];    // 16 KB
    __shared__ __align__(16) unsigned char Bs[2][BN][BK];    // 32 KB
    __shared__ float invn_sh[BM];                            // 0.5 KB

    // bijective XCD swizzle (3128 = 8*391): consecutive logicals on one XCD
    // share a target panel (4 source chunks) -> panel HBM-read once.
    const int b = blockIdx.x;
    const int logical = (b & 7) * (NBLK / 8) + (b >> 3);
    const int mblk = logical >> 2;          // 0..781
    const int schk = logical & 3;           // 0..3
    const int m0 = mblk * BM;
    const int c0 = schk * BN;

    const int t = threadIdx.x;
    const int lane = t & 63;
    const int w = t >> 6;                   // 8 waves
    const int wm = w >> 2, wn = w & 3;      // 2M x 4N, per-wave 64x64
    const int g = lane >> 4, li = lane & 15;

    const char* tb_ = (const char*)tgtbf;
    const char* sb_ = (const char*)srcbf;

    f32x4 acc[4][4];
    #pragma unroll
    for (int i = 0; i < 4; ++i)
        #pragma unroll
        for (int j = 0; j < 4; ++j) acc[i][j] = (f32x4){0.f, 0.f, 0.f, 0.f};

    unsigned char *Ac = &As[0][0][0], *An = &As[1][0][0];
    unsigned char *Bc = &Bs[0][0][0], *Bn = &Bs[1][0][0];

    // stage: A tile 8KB = 1 gload/thread, B tile 16KB = 2 gloads/thread.
    #define STAGE(Ab_, Bb_, kt_) do {                                         \
        const char* ga_ = tb_ + (size_t)(kt_) * TGT_KT_B + (size_t)m0 * 64    \
                          + (size_t)t * 16;                                   \
        gload16(ga_, (Ab_) + t * 16);                                         \
        const char* gb_ = sb_ + (size_t)(kt_) * SRC_KT_B + (size_t)c0 * 64    \
                          + (size_t)t * 16;                                   \
        gload16(gb_,        (Bb_) + t * 16);                                  \
        gload16(gb_ + 8192, (Bb_) + 8192 + t * 16);                           \
    } while (0)

    // frag read: content chunk g at LDS position g ^ ((row>>1)&3); frag rows
    // are base + mf*16 + li (base % 16 == 0) so (row>>1)&3 == (li>>1)&3.
    // Each b128 = {kw0 8B frag, kw1 8B frag}.
    const int sl = (g ^ ((li >> 1) & 3)) * 16;

    #define READ_AB do {                                                      \
        _Pragma("unroll")                                                     \
        for (int mf = 0; mf < 4; ++mf)                                        \
            af[mf] = *(const i64x2*)(Ac + (wm * 64 + mf * 16 + li) * BK + sl);\
        _Pragma("unroll")                                                     \
        for (int nf = 0; nf < 4; ++nf)                                        \
            bf[nf] = *(const i64x2*)(Bc + (wn * 64 + nf * 16 + li) * BK + sl);\
    } while (0)

    #define DO_MFMA do {                                                      \
        _Pragma("unroll")                                                     \
        for (int mf = 0; mf < 4; ++mf)                                        \
            _Pragma("unroll")                                                 \
            for (int nf = 0; nf < 4; ++nf)                                    \
                acc[mf][nf] = __builtin_amdgcn_mfma_f32_16x16x32_fp8_fp8(     \
                    af[mf][0], bf[nf][0], acc[mf][nf], 0, 0, 0);              \
        _Pragma("unroll")                                                     \
        for (int mf = 0; mf < 4; ++mf)                                        \
            _Pragma("unroll")                                                 \
            for (int nf = 0; nf < 4; ++nf)                                    \
                acc[mf][nf] = __builtin_amdgcn_mfma_f32_16x16x32_fp8_fp8(     \
                    af[mf][1], bf[nf][1], acc[mf][nf], 0, 0, 0);              \
    } while (0)

    // ---- prologue: stage tile 0 (syncthreads drains vmcnt+lgkmcnt)
    STAGE(Ac, Bc, 0);
    __syncthreads();

    // ---- main loop: one barrier per K-tile (K=64)
    for (int kt = 0; kt < NKT; ++kt) {
        if (kt + 1 < NKT) STAGE(An, Bn, kt + 1);
        i64x2 af[4], bf[4];
        READ_AB;
        DO_MFMA;
        __syncthreads();
        unsigned char* tmp_;
        tmp_ = Ac; Ac = An; An = tmp_;
        tmp_ = Bc; Bc = Bn; Bn = tmp_;
    }
    #undef STAGE
    #undef READ_AB
    #undef DO_MFMA

    // ---- epilogue (scratch aliased onto As[0]/As[1], both dead now;
    //      the loop's final __syncthreads() drained all ds_reads) -----------
    float* scv = (float*)&As[0][0][0];                   // 8 KB: 2*BN*KNN f32
    int*   sci = (int*)&As[1][0][0];                     // 8 KB

    if (t < BM) invn_sh[t] = invnw[m0 + t];
    __syncthreads();

    float invr[4][4];
    #pragma unroll
    for (int mf = 0; mf < 4; ++mf)
        #pragma unroll
        for (int j = 0; j < 4; ++j)
            invr[mf][j] = invn_sh[wm * 64 + mf * 16 + g * 4 + j];

    // per-wave top-4 per source column over the wave's 64 target rows
    #pragma unroll
    for (int nf = 0; nf < 4; ++nf) {
        const int col = wn * 64 + nf * 16 + li;          // 0..255
        float s[4][4];
        #pragma unroll
        for (int mf = 0; mf < 4; ++mf)
            #pragma unroll
            for (int j = 0; j < 4; ++j)
                s[mf][j] = (invr[mf][j] > 0.f) ? acc[mf][nf][j] * invr[mf][j]
                                               : -FLT_MAX;
        #pragma unroll
        for (int it = 0; it < KNN; ++it) {
            float bv = -FLT_MAX; int bli = 0;
            #pragma unroll
            for (int mf = 0; mf < 4; ++mf)
                #pragma unroll
                for (int j = 0; j < 4; ++j) {
                    int id = mf * 16 + g * 4 + j;
                    if (s[mf][j] > bv) { bv = s[mf][j]; bli = id; }
                }
            #pragma unroll
            for (int off = 16; off < 64; off <<= 1) {
                float ov = __shfl_xor(bv, off);
                int   oi = __shfl_xor(bli, off);
                if (ov > bv || (ov == bv && oi < bli)) { bv = ov; bli = oi; }
            }
            const int mfw = bli >> 4, gw = (bli >> 2) & 3, jw = bli & 3;
            if (g == gw) {
                #pragma unroll
                for (int mf = 0; mf < 4; ++mf)
                    #pragma unroll
                    for (int j = 0; j < 4; ++j)
                        if (mf == mfw && j == jw) s[mf][j] = -FLT_MAX;
            }
            if (g == it) {
                int o = (wm * BN + col) * KNN + it;
                scv[o] = bv;
                sci[o] = m0 + wm * 64 + bli;             // global target row
            }
        }
    }
    __syncthreads();

    // merge the two wm halves: thread t<256 -> top-4 of 8 for column t
    if (t < BN) {
        float v4[4] = { -FLT_MAX, -FLT_MAX, -FLT_MAX, -FLT_MAX };
        int   i4[4] = { 0x7fffffff, 0x7fffffff, 0x7fffffff, 0x7fffffff };
        #pragma unroll
        for (int q = 0; q < 8; ++q) {
            int o = ((q >> 2) * BN + t) * KNN + (q & 3);
            float v = scv[o]; int ix = sci[o];
            if (v > v4[3] || (v == v4[3] && ix < i4[3])) {
                v4[3] = v; i4[3] = ix;
                ce_desc(v4[2], i4[2], v4[3], i4[3]);
                ce_desc(v4[1], i4[1], v4[2], i4[2]);
                ce_desc(v4[0], i4[0], v4[1], i4[1]);
            }
        }
        size_t o = ((size_t)(c0 + t) * NSTRIP + mblk) * KNN;
        #pragma unroll
        for (int it = 0; it < KNN; ++it) {
            cand_val[o + it] = v4[it];
            cand_idx[o + it] = i4[it];
        }
    }
}

// ---------------------------------------------------------------------------
// Kernel 3: per source row — candidate top-32, exact f32 rerank, top-4,
// gather + mean. One block (256 thr) per row.
// ---------------------------------------------------------------------------
__global__ __launch_bounds__(256) void merge_rerank_kernel(
    const float* __restrict__ src, const float* __restrict__ tgt,
    const float* __restrict__ cand_val, const int* __restrict__ cand_idx,
    float* __restrict__ out)
{
    __shared__ float sv[NCAND];          // 12.5 KB
    __shared__ float red_v[4];
    __shared__ int   red_p[4];
    __shared__ int   topi[RERANK];
    __shared__ float rsim[RERANK];
    __shared__ int   ridx[RERANK];
    __shared__ int   sel[KNN];

    const int row = blockIdx.x;
    const int t = threadIdx.x, lane = t & 63, w = t >> 6;
    const float* cv = cand_val + (size_t)row * NCAND;
    const int*   ci = cand_idx + (size_t)row * NCAND;

    for (int i = t; i < NCAND; i += 256) sv[i] = cv[i];
    __syncthreads();

    for (int it = 0; it < RERANK; ++it) {
        float bv = -FLT_MAX; int bp = 0;
        for (int i = t; i < NCAND; i += 256) {
            float v = sv[i];
            if (v > bv) { bv = v; bp = i; }
        }
        #pragma unroll
        for (int off = 1; off < 64; off <<= 1) {
            float ov = __shfl_xor(bv, off);
            int   op = __shfl_xor(bp, off);
            if (ov > bv || (ov == bv && op < bp)) { bv = ov; bp = op; }
        }
        if (lane == 0) { red_v[w] = bv; red_p[w] = bp; }
        __syncthreads();
        if (t == 0) {
            float Bv = red_v[0]; int Bp = red_p[0];
            for (int q = 1; q < 4; ++q)
                if (red_v[q] > Bv || (red_v[q] == Bv && red_p[q] < Bp)) {
                    Bv = red_v[q]; Bp = red_p[q];
                }
            topi[it] = ci[Bp];
            sv[Bp] = -FLT_MAX;
        }
        __syncthreads();
    }

    // exact f32 rerank: dot AND target norm from the same row read
    const float4* sp = (const float4*)(src + (size_t)row * DIM);
    #pragma unroll
    for (int q = 0; q < 8; ++q) {
        int cidx = topi[w + 4 * q];
        const float4* tp = (const float4*)(tgt + (size_t)cidx * DIM);
        float a = 0.f, nn = 0.f;
        #pragma unroll
        for (int p = 0; p < 4; ++p) {
            float4 x = sp[lane + 64 * p], y = tp[lane + 64 * p];
            a  = fmaf(x.x, y.x, a);  a  = fmaf(x.y, y.y, a);
            a  = fmaf(x.z, y.z, a);  a  = fmaf(x.w, y.w, a);
            nn = fmaf(y.x, y.x, nn); nn = fmaf(y.y, y.y, nn);
            nn = fmaf(y.z, y.z, nn); nn = fmaf(y.w, y.w, nn);
        }
        #pragma unroll
        for (int off = 1; off < 64; off <<= 1) {
            a  += __shfl_xor(a, off);
            nn += __shfl_xor(nn, off);
        }
        if (lane == 0) { rsim[w + 4 * q] = a / sqrtf(nn); ridx[w + 4 * q] = cidx; }
    }
    __syncthreads();

    if (w == 0) {
        float v = (lane < RERANK) ? rsim[lane] : -FLT_MAX;
        int  ix = (lane < RERANK) ? ridx[lane] : 0x7fffffff;
        #pragma unroll
        for (int it = 0; it < KNN; ++it) {
            float bv = v; int bix = ix;
            #pragma unroll
            for (int off = 1; off < 32; off <<= 1) {
                float ov = __shfl_xor(bv, off);
                int   oi = __shfl_xor(bix, off);
                if (ov > bv || (ov == bv && oi < bix)) { bv = ov; bix = oi; }
            }
            if (lane == 0) sel[it] = bix;
            if (ix == bix) v = -FLT_MAX;
        }
    }
    __syncthreads();

    const float4* g0 = (const float4*)(tgt + (size_t)sel[0] * DIM);
    const float4* g1 = (const float4*)(tgt + (size_t)sel[1] * DIM);
    const float4* g2 = (const float4*)(tgt + (size_t)sel[2] * DIM);
    const float4* g3 = (const float4*)(tgt + (size_t)sel[3] * DIM);
    float4* po = (float4*)(out + (size_t)row * DIM);
    float4 v0 = g0[t], v1 = g1[t], v2 = g2[t], v3 = g3[t];
    float4 rr;
    rr.x = (v0.x + v1.x + v2.x + v3.x) * 0.25f;
    rr.y = (v0.y + v1.y + v2.y + v3.y) * 0.25f;
    rr.z = (v0.z + v1.z + v2.z + v3.z) * 0.25f;
    rr.w = (v0.w + v1.w + v2.w + v3.w) * 0.25f;
    po[t] = rr;
}

// ---------------------------------------------------------------------------
extern "C" void kernel_launch(void* const* d_in, const int* in_sizes, int n_in,
                              void* d_out, int out_size, void* d_ws, size_t ws_size,
                              hipStream_t stream)
{
    const float* src = (const float*)d_in[0];
    const float* tgt = (const float*)d_in[1];
    float* out = (float*)d_out;

    const size_t SRCBF_B = 2097152;                       // 1 MB used, 2 MB reserved
    const size_t TGTBF_B = (size_t)N_TGT2 * 1024;         // ~102.5 MB (16 planes x 64B)
    const size_t INVN_B  = (size_t)N_TGT2 * 4;            // 0.4 MB
    const size_t CV_B    = (size_t)N_SRC * NCAND * 4;     // 12.8 MB

    char* p = (char*)d_ws;
    unsigned int* srcbf = (unsigned int*)p;
    unsigned int* tgtbf = (unsigned int*)(p + SRCBF_B);
    float* invnw    = (float*)(p + SRCBF_B + TGTBF_B);
    float* cand_val = (float*)(p + SRCBF_B + TGTBF_B + INVN_B);
    int*   cand_idx = (int*)(p + SRCBF_B + TGTBF_B + INVN_B + CV_B);

    convert_src_kernel<<<256, 256, 0, stream>>>(src, srcbf);
    prep_tgt_kernel<<<N_TGT2 / 16, 256, 0, stream>>>(tgt, tgtbf, invnw);
    gemm_topk_fp8_kernel<<<NBLK, 512, 0, stream>>>(tgtbf, srcbf, invnw,
                                                   cand_val, cand_idx);
    merge_rerank_kernel<<<N_SRC, 256, 0, stream>>>(src, tgt,
                                                   cand_val, cand_idx, out);
}

// Round 13
// 374.126 us; speedup vs baseline: 3.5279x; 1.0710x over previous
//
#include <hip/hip_runtime.h>
#include <hip/hip_bf16.h>
#include <float.h>

#define N_SRC 1024
#define N_TGT 100000
#define DIM   1024
#define KNN   4

// GEMM geometry: M = targets (128/block), N = sources (256/block), BK=64 (fp8).
#define BM 128
#define BN 256
#define BK 64
#define NKT (DIM / BK)               // 16 K-tiles
#define NMB 782                      // target panels (782*128 = 100096)
#define N_TGT2 (NMB * BM)            // 100096 padded target rows
#define NSC (N_SRC / BN)             // 4 source chunks
#define NBLK (NMB * NSC)             // 3128
#define NSTRIP NMB                   // one 128-row strip per panel
#define NCAND (NSTRIP * KNN)         // 3128 candidates per source row
#define RERANK 32                    // widened for fp8 selection noise

#define SRC_KT_B 65536ull                              // src ws bytes per kt-plane
#define TGT_KT_B ((unsigned long long)N_TGT2 * 64ull)  // tgt ws bytes per kt-plane

typedef __attribute__((ext_vector_type(4))) float f32x4;
typedef __attribute__((ext_vector_type(4))) unsigned int u32x4;
typedef __attribute__((ext_vector_type(2))) long long i64x2;

__device__ __forceinline__ void gload16(const void* gp, void* lp) {
    __builtin_amdgcn_global_load_lds(
        (const __attribute__((address_space(1))) void*)gp,
        (__attribute__((address_space(3))) void*)lp, 16, 0, 0);
}

// pack 4 f32 -> 4 fp8 e4m3 (RNE, OCP on gfx950) in one dword, k-order x0..x3
__device__ __forceinline__ unsigned int pk_fp8x4(float x0, float x1,
                                                 float x2, float x3) {
    int d = __builtin_amdgcn_cvt_pk_fp8_f32(x0, x1, 0, false);   // bytes 0,1
    d     = __builtin_amdgcn_cvt_pk_fp8_f32(x2, x3, d, true);    // bytes 2,3
    return (unsigned int)d;
}

// sorted-desc compare-exchange: (v1,i1) keeps the greater (tie -> lower idx)
__device__ __forceinline__ void ce_desc(float& v1, int& i1, float& v2, int& i2)
{
    bool sw = (v2 > v1) || (v2 == v1 && i2 < i1);
    float tv = sw ? v2 : v1; float uv = sw ? v1 : v2;
    int   ti = sw ? i2 : i1; int   ui = sw ? i1 : i2;
    v1 = tv; i1 = ti; v2 = uv; i2 = ui;
}

// ---------------------------------------------------------------------------
// Kernel 1: sources f32 -> fp8 ws, layout [kt16][1024 rows][4 pos x 16B].
// Position p of a row holds content chunk c = p ^ ((row>>1)&3):
// bytes 0..7  = fp8(k = kt*64 + c*8 + 0..7)         (kw0 half)
// bytes 8..15 = fp8(k = kt*64 + 32 + c*8 + 0..7)    (kw1 half)
// ---------------------------------------------------------------------------
__global__ __launch_bounds__(256) void convert_src_kernel(
    const float* __restrict__ src, unsigned int* __restrict__ srcws)
{
    int gid = blockIdx.x * 256 + threadIdx.x;   // 16B position id; 65536 total
    int kt  = gid >> 12;                        // 0..15
    int rem = gid & 4095;
    int row = rem >> 2;
    int pos = rem & 3;
    int c   = pos ^ ((row >> 1) & 3);
    const float4* p0 = (const float4*)(src + (size_t)row * DIM + kt * BK + c * 8);
    const float4* p1 = (const float4*)(src + (size_t)row * DIM + kt * BK + 32 + c * 8);
    float4 a0 = p0[0], a1 = p0[1], b0 = p1[0], b1 = p1[1];
    u32x4 o = { pk_fp8x4(a0.x, a0.y, a0.z, a0.w),
                pk_fp8x4(a1.x, a1.y, a1.z, a1.w),
                pk_fp8x4(b0.x, b0.y, b0.z, b0.w),
                pk_fp8x4(b1.x, b1.y, b1.z, b1.w) };
    ((u32x4*)srcws)[gid] = o;
}

// ---------------------------------------------------------------------------
// Kernel 1b: targets f32 -> fp8 ws, same layout [kt16][N_TGT2 rows][4 x 16B],
// PLUS exact f32 inverse norms. Thread t: row = blk*16 + (t&15), kt = t>>4.
// ---------------------------------------------------------------------------
__global__ __launch_bounds__(256) void prep_tgt_kernel(
    const float* __restrict__ tgt, unsigned int* __restrict__ tgtbf,
    float* __restrict__ invnw)
{
    __shared__ float pn[16][17];
    const int t  = threadIdx.x;
    const int li = t & 15;
    const int kt = t >> 4;
    const int row = blockIdx.x * 16 + li;
    const bool valid = row < N_TGT;

    float4 v[16];
    if (valid) {
        const float4* p = (const float4*)(tgt + (size_t)row * DIM + kt * BK);
        #pragma unroll
        for (int i = 0; i < 16; ++i) v[i] = p[i];
    } else {
        #pragma unroll
        for (int i = 0; i < 16; ++i) v[i] = make_float4(0.f, 0.f, 0.f, 0.f);
    }
    float nsq = 0.f;
    #pragma unroll
    for (int i = 0; i < 16; ++i)
        nsq += v[i].x * v[i].x + v[i].y * v[i].y
             + v[i].z * v[i].z + v[i].w * v[i].w;

    u32x4* o = (u32x4*)((char*)tgtbf + (size_t)kt * TGT_KT_B
                        + (size_t)row * 64);
    const int f = (row >> 1) & 3;
    #pragma unroll
    for (int c = 0; c < 4; ++c) {
        float4 a0 = v[2 * c], a1 = v[2 * c + 1];        // kw0: k = c*8..c*8+7
        float4 b0 = v[8 + 2 * c], b1 = v[8 + 2 * c + 1];// kw1: k = 32+c*8..+7
        o[c ^ f] = (u32x4){ pk_fp8x4(a0.x, a0.y, a0.z, a0.w),
                            pk_fp8x4(a1.x, a1.y, a1.z, a1.w),
                            pk_fp8x4(b0.x, b0.y, b0.z, b0.w),
                            pk_fp8x4(b1.x, b1.y, b1.z, b1.w) };
    }

    pn[li][kt] = nsq;
    __syncthreads();
    if (t < 16) {
        float s = 0.f;
        #pragma unroll
        for (int k = 0; k < 16; ++k) s += pn[t][k];
        int r2 = blockIdx.x * 16 + t;
        invnw[r2] = (r2 < N_TGT) ? 1.0f / sqrtf(s) : -1.0f;
    }
}

// ---------------------------------------------------------------------------
// Kernel 2: fp8 MFMA GEMM, 128x256 tile, BK=64, 8 waves (wave 64x64).
// PHASES x COUNTED-VMCNT combined (the untested cell of the 2x2; m218's
// winning configuration): 3 LDS buffers, per K-tile 2 phases of
// {ds_read sub-frags | issue gload kt+2} -> s_barrier -> lgkmcnt(0) ->
// setprio(1) -> 16 MFMA -> setprio(0) -> s_barrier, with ONE counted
// vmcnt(3) per tile (kt+2's 3 loads stay in flight across barriers).
// 72.5 KB LDS -> 2 blocks/CU. Epilogue scratch aliased onto dead A-bufs.
// ---------------------------------------------------------------------------
__global__ __launch_bounds__(512, 4) void gemm_topk_fp8_kernel(
    const void* __restrict__ tgtbf, const void* __restrict__ srcbf,
    const float* __restrict__ invnw,
    float* __restrict__ cand_val, int* __restrict__ cand_idx)
{
    __shared__ __align__(16) unsigned char As[3][BM][BK];    // 24 KB
    __shared__ __align__(16) unsigned char Bs[3][BN][BK];    // 48 KB
    __shared__ float invn_sh[BM];                            // 0.5 KB

    // bijective XCD swizzle (3128 = 8*391): consecutive logicals on one XCD
    // share a target panel (4 source chunks) -> panel HBM-read once.
    const int b = blockIdx.x;
    const int logical = (b & 7) * (NBLK / 8) + (b >> 3);
    const int mblk = logical >> 2;          // 0..781
    const int schk = logical & 3;           // 0..3
    const int m0 = mblk * BM;
    const int c0 = schk * BN;

    const int t = threadIdx.x;
    const int lane = t & 63;
    const int w = t >> 6;                   // 8 waves
    const int wm = w >> 2, wn = w & 3;      // 2M x 4N, per-wave 64x64
    const int g = lane >> 4, li = lane & 15;

    const char* tb_ = (const char*)tgtbf;
    const char* sb_ = (const char*)srcbf;

    f32x4 acc[4][4];
    #pragma unroll
    for (int i = 0; i < 4; ++i)
        #pragma unroll
        for (int j = 0; j < 4; ++j) acc[i][j] = (f32x4){0.f, 0.f, 0.f, 0.f};

    unsigned char *Ac = &As[0][0][0], *An1 = &As[1][0][0], *An2 = &As[2][0][0];
    unsigned char *Bc = &Bs[0][0][0], *Bn1 = &Bs[1][0][0], *Bn2 = &Bs[2][0][0];

    // stage pieces: A tile 8KB = 1 gload/thread; B tile 16KB = 2 gloads.
    #define STAGE_A(Ab_, kt_) do {                                            \
        gload16(tb_ + (size_t)(kt_) * TGT_KT_B + (size_t)m0 * 64              \
                + (size_t)t * 16, (Ab_) + t * 16);                            \
    } while (0)
    #define STAGE_B1(Bb_, kt_) do {                                           \
        gload16(sb_ + (size_t)(kt_) * SRC_KT_B + (size_t)c0 * 64              \
                + (size_t)t * 16, (Bb_) + t * 16);                            \
    } while (0)
    #define STAGE_B2(Bb_, kt_) do {                                           \
        gload16(sb_ + (size_t)(kt_) * SRC_KT_B + (size_t)c0 * 64 + 8192       \
                + (size_t)t * 16, (Bb_) + 8192 + t * 16);                     \
    } while (0)

    // frag read: content chunk g at LDS position g ^ ((row>>1)&3); frag rows
    // are base + mf*16 + li (base % 16 == 0) so (row>>1)&3 == (li>>1)&3.
    // Each b128 = {kw0 8B frag, kw1 8B frag}.
    const int sl = (g ^ ((li >> 1) & 3)) * 16;

    #define READ_A4 do {                                                      \
        _Pragma("unroll")                                                     \
        for (int mf = 0; mf < 4; ++mf)                                        \
            af[mf] = *(const i64x2*)(Ac + (wm * 64 + mf * 16 + li) * BK + sl);\
    } while (0)
    #define READ_B01 do {                                                     \
        bf[0] = *(const i64x2*)(Bc + (wn * 64 +  0 + li) * BK + sl);          \
        bf[1] = *(const i64x2*)(Bc + (wn * 64 + 16 + li) * BK + sl);          \
    } while (0)
    #define READ_B23 do {                                                     \
        bf[2] = *(const i64x2*)(Bc + (wn * 64 + 32 + li) * BK + sl);          \
        bf[3] = *(const i64x2*)(Bc + (wn * 64 + 48 + li) * BK + sl);          \
    } while (0)

    // 16 MFMA for nf pair {n0_, n0_+1}, both kw halves
    #define MFMA_NPAIR(n0_) do {                                              \
        _Pragma("unroll")                                                     \
        for (int mf = 0; mf < 4; ++mf)                                        \
            _Pragma("unroll")                                                 \
            for (int nf = (n0_); nf < (n0_) + 2; ++nf)                        \
                acc[mf][nf] = __builtin_amdgcn_mfma_f32_16x16x32_fp8_fp8(     \
                    af[mf][0], bf[nf][0], acc[mf][nf], 0, 0, 0);              \
        _Pragma("unroll")                                                     \
        for (int mf = 0; mf < 4; ++mf)                                        \
            _Pragma("unroll")                                                 \
            for (int nf = (n0_); nf < (n0_) + 2; ++nf)                        \
                acc[mf][nf] = __builtin_amdgcn_mfma_f32_16x16x32_fp8_fp8(     \
                    af[mf][1], bf[nf][1], acc[mf][nf], 0, 0, 0);              \
    } while (0)

    #define PH_ENTER do {                                                     \
        __builtin_amdgcn_s_barrier();                                         \
        asm volatile("s_waitcnt lgkmcnt(0)" ::: "memory");                    \
        __builtin_amdgcn_sched_barrier(0);                                    \
        __builtin_amdgcn_s_setprio(1);                                        \
    } while (0)
    #define PH_EXIT do {                                                      \
        __builtin_amdgcn_s_setprio(0);                                        \
        __builtin_amdgcn_s_barrier();                                         \
    } while (0)
    #define ROTATE do {                                                       \
        unsigned char* tmp_;                                                  \
        tmp_ = Ac; Ac = An1; An1 = An2; An2 = tmp_;                           \
        tmp_ = Bc; Bc = Bn1; Bn1 = Bn2; Bn2 = tmp_;                           \
    } while (0)

    // ---- prologue: issue kt0 (oldest 3) + kt1 (3); drain kt0 only
    STAGE_A(Ac, 0);  STAGE_B1(Bc, 0);  STAGE_B2(Bc, 0);
    STAGE_A(An1, 1); STAGE_B1(Bn1, 1); STAGE_B2(Bn1, 1);
    asm volatile("s_waitcnt vmcnt(3)" ::: "memory");
    __builtin_amdgcn_sched_barrier(0);
    __builtin_amdgcn_s_barrier();

    // ---- steady loop: kt = 0..13, issue kt+2 split across the 2 phases
    for (int kt = 0; kt < NKT - 2; ++kt) {
        i64x2 af[4], bf[4];
        // phase 0: frags {A all, B 0-1} | stage A + B#1 of kt+2
        READ_A4;
        READ_B01;
        STAGE_A(An2, kt + 2);
        STAGE_B1(Bn2, kt + 2);
        PH_ENTER;
        MFMA_NPAIR(0);
        PH_EXIT;
        // phase 1: frags {B 2-3} | stage B#2 of kt+2 | counted wait on kt+1
        READ_B23;
        STAGE_B2(Bn2, kt + 2);
        asm volatile("s_waitcnt vmcnt(3)" ::: "memory");  // drain kt+1's 3
        __builtin_amdgcn_sched_barrier(0);
        PH_ENTER;
        MFMA_NPAIR(2);
        PH_EXIT;
        ROTATE;
    }
    {   // kt = 14: no issues; full drain of kt15's loads at phase 1
        i64x2 af[4], bf[4];
        READ_A4;
        READ_B01;
        PH_ENTER;
        MFMA_NPAIR(0);
        PH_EXIT;
        READ_B23;
        asm volatile("s_waitcnt vmcnt(0)" ::: "memory");
        __builtin_amdgcn_sched_barrier(0);
        PH_ENTER;
        MFMA_NPAIR(2);
        PH_EXIT;
        ROTATE;
    }
    {   // kt = 15: compute only
        i64x2 af[4], bf[4];
        READ_A4;
        READ_B01;
        PH_ENTER;
        MFMA_NPAIR(0);
        PH_EXIT;
        READ_B23;
        PH_ENTER;
        MFMA_NPAIR(2);
        PH_EXIT;
        __syncthreads();   // all waves' ds_reads done -> safe to alias LDS
    }
    #undef STAGE_A
    #undef STAGE_B1
    #undef STAGE_B2
    #undef READ_A4
    #undef READ_B01
    #undef READ_B23
    #undef MFMA_NPAIR
    #undef PH_ENTER
    #undef PH_EXIT
    #undef ROTATE

    // ---- epilogue (scratch aliased onto As[0]/As[1], both dead now) -------
    float* scv = (float*)&As[0][0][0];                   // 8 KB: 2*BN*KNN f32
    int*   sci = (int*)&As[1][0][0];                     // 8 KB

    if (t < BM) invn_sh[t] = invnw[m0 + t];
    __syncthreads();

    float invr[4][4];
    #pragma unroll
    for (int mf = 0; mf < 4; ++mf)
        #pragma unroll
        for (int j = 0; j < 4; ++j)
            invr[mf][j] = invn_sh[wm * 64 + mf * 16 + g * 4 + j];

    // per-wave top-4 per source column over the wave's 64 target rows
    #pragma unroll
    for (int nf = 0; nf < 4; ++nf) {
        const int col = wn * 64 + nf * 16 + li;          // 0..255
        float s[4][4];
        #pragma unroll
        for (int mf = 0; mf < 4; ++mf)
            #pragma unroll
            for (int j = 0; j < 4; ++j)
                s[mf][j] = (invr[mf][j] > 0.f) ? acc[mf][nf][j] * invr[mf][j]
                                               : -FLT_MAX;
        #pragma unroll
        for (int it = 0; it < KNN; ++it) {
            float bv = -FLT_MAX; int bli = 0;
            #pragma unroll
            for (int mf = 0; mf < 4; ++mf)
                #pragma unroll
                for (int j = 0; j < 4; ++j) {
                    int id = mf * 16 + g * 4 + j;
                    if (s[mf][j] > bv) { bv = s[mf][j]; bli = id; }
                }
            #pragma unroll
            for (int off = 16; off < 64; off <<= 1) {
                float ov = __shfl_xor(bv, off);
                int   oi = __shfl_xor(bli, off);
                if (ov > bv || (ov == bv && oi < bli)) { bv = ov; bli = oi; }
            }
            const int mfw = bli >> 4, gw = (bli >> 2) & 3, jw = bli & 3;
            if (g == gw) {
                #pragma unroll
                for (int mf = 0; mf < 4; ++mf)
                    #pragma unroll
                    for (int j = 0; j < 4; ++j)
                        if (mf == mfw && j == jw) s[mf][j] = -FLT_MAX;
            }
            if (g == it) {
                int o = (wm * BN + col) * KNN + it;
                scv[o] = bv;
                sci[o] = m0 + wm * 64 + bli;             // global target row
            }
        }
    }
    __syncthreads();

    // merge the two wm halves: thread t<256 -> top-4 of 8 for column t
    if (t < BN) {
        float v4[4] = { -FLT_MAX, -FLT_MAX, -FLT_MAX, -FLT_MAX };
        int   i4[4] = { 0x7fffffff, 0x7fffffff, 0x7fffffff, 0x7fffffff };
        #pragma unroll
        for (int q = 0; q < 8; ++q) {
            int o = ((q >> 2) * BN + t) * KNN + (q & 3);
            float v = scv[o]; int ix = sci[o];
            if (v > v4[3] || (v == v4[3] && ix < i4[3])) {
                v4[3] = v; i4[3] = ix;
                ce_desc(v4[2], i4[2], v4[3], i4[3]);
                ce_desc(v4[1], i4[1], v4[2], i4[2]);
                ce_desc(v4[0], i4[0], v4[1], i4[1]);
            }
        }
        size_t o = ((size_t)(c0 + t) * NSTRIP + mblk) * KNN;
        #pragma unroll
        for (int it = 0; it < KNN; ++it) {
            cand_val[o + it] = v4[it];
            cand_idx[o + it] = i4[it];
        }
    }
}

// ---------------------------------------------------------------------------
// Kernel 3: per source row — candidate top-32, exact f32 rerank, top-4,
// gather + mean. One block (256 thr) per row.
// ---------------------------------------------------------------------------
__global__ __launch_bounds__(256) void merge_rerank_kernel(
    const float* __restrict__ src, const float* __restrict__ tgt,
    const float* __restrict__ cand_val, const int* __restrict__ cand_idx,
    float* __restrict__ out)
{
    __shared__ float sv[NCAND];          // 12.5 KB
    __shared__ float red_v[4];
    __shared__ int   red_p[4];
    __shared__ int   topi[RERANK];
    __shared__ float rsim[RERANK];
    __shared__ int   ridx[RERANK];
    __shared__ int   sel[KNN];

    const int row = blockIdx.x;
    const int t = threadIdx.x, lane = t & 63, w = t >> 6;
    const float* cv = cand_val + (size_t)row * NCAND;
    const int*   ci = cand_idx + (size_t)row * NCAND;

    for (int i = t; i < NCAND; i += 256) sv[i] = cv[i];
    __syncthreads();

    for (int it = 0; it < RERANK; ++it) {
        float bv = -FLT_MAX; int bp = 0;
        for (int i = t; i < NCAND; i += 256) {
            float v = sv[i];
            if (v > bv) { bv = v; bp = i; }
        }
        #pragma unroll
        for (int off = 1; off < 64; off <<= 1) {
            float ov = __shfl_xor(bv, off);
            int   op = __shfl_xor(bp, off);
            if (ov > bv || (ov == bv && op < bp)) { bv = ov; bp = op; }
        }
        if (lane == 0) { red_v[w] = bv; red_p[w] = bp; }
        __syncthreads();
        if (t == 0) {
            float Bv = red_v[0]; int Bp = red_p[0];
            for (int q = 1; q < 4; ++q)
                if (red_v[q] > Bv || (red_v[q] == Bv && red_p[q] < Bp)) {
                    Bv = red_v[q]; Bp = red_p[q];
                }
            topi[it] = ci[Bp];
            sv[Bp] = -FLT_MAX;
        }
        __syncthreads();
    }

    // exact f32 rerank: dot AND target norm from the same row read
    const float4* sp = (const float4*)(src + (size_t)row * DIM);
    #pragma unroll
    for (int q = 0; q < 8; ++q) {
        int cidx = topi[w + 4 * q];
        const float4* tp = (const float4*)(tgt + (size_t)cidx * DIM);
        float a = 0.f, nn = 0.f;
        #pragma unroll
        for (int p = 0; p < 4; ++p) {
            float4 x = sp[lane + 64 * p], y = tp[lane + 64 * p];
            a  = fmaf(x.x, y.x, a);  a  = fmaf(x.y, y.y, a);
            a  = fmaf(x.z, y.z, a);  a  = fmaf(x.w, y.w, a);
            nn = fmaf(y.x, y.x, nn); nn = fmaf(y.y, y.y, nn);
            nn = fmaf(y.z, y.z, nn); nn = fmaf(y.w, y.w, nn);
        }
        #pragma unroll
        for (int off = 1; off < 64; off <<= 1) {
            a  += __shfl_xor(a, off);
            nn += __shfl_xor(nn, off);
        }
        if (lane == 0) { rsim[w + 4 * q] = a / sqrtf(nn); ridx[w + 4 * q] = cidx; }
    }
    __syncthreads();

    if (w == 0) {
        float v = (lane < RERANK) ? rsim[lane] : -FLT_MAX;
        int  ix = (lane < RERANK) ? ridx[lane] : 0x7fffffff;
        #pragma unroll
        for (int it = 0; it < KNN; ++it) {
            float bv = v; int bix = ix;
            #pragma unroll
            for (int off = 1; off < 32; off <<= 1) {
                float ov = __shfl_xor(bv, off);
                int   oi = __shfl_xor(bix, off);
                if (ov > bv || (ov == bv && oi < bix)) { bv = ov; bix = oi; }
            }
            if (lane == 0) sel[it] = bix;
            if (ix == bix) v = -FLT_MAX;
        }
    }
    __syncthreads();

    const float4* g0 = (const float4*)(tgt + (size_t)sel[0] * DIM);
    const float4* g1 = (const float4*)(tgt + (size_t)sel[1] * DIM);
    const float4* g2 = (const float4*)(tgt + (size_t)sel[2] * DIM);
    const float4* g3 = (const float4*)(tgt + (size_t)sel[3] * DIM);
    float4* po = (float4*)(out + (size_t)row * DIM);
    float4 v0 = g0[t], v1 = g1[t], v2 = g2[t], v3 = g3[t];
    float4 rr;
    rr.x = (v0.x + v1.x + v2.x + v3.x) * 0.25f;
    rr.y = (v0.y + v1.y + v2.y + v3.y) * 0.25f;
    rr.z = (v0.z + v1.z + v2.z + v3.z) * 0.25f;
    rr.w = (v0.w + v1.w + v2.w + v3.w) * 0.25f;
    po[t] = rr;
}

// ---------------------------------------------------------------------------
extern "C" void kernel_launch(void* const* d_in, const int* in_sizes, int n_in,
                              void* d_out, int out_size, void* d_ws, size_t ws_size,
                              hipStream_t stream)
{
    const float* src = (const float*)d_in[0];
    const float* tgt = (const float*)d_in[1];
    float* out = (float*)d_out;

    const size_t SRCBF_B = 2097152;                       // 1 MB used, 2 MB reserved
    const size_t TGTBF_B = (size_t)N_TGT2 * 1024;         // ~102.5 MB (16 planes x 64B)
    const size_t INVN_B  = (size_t)N_TGT2 * 4;            // 0.4 MB
    const size_t CV_B    = (size_t)N_SRC * NCAND * 4;     // 12.8 MB

    char* p = (char*)d_ws;
    unsigned int* srcbf = (unsigned int*)p;
    unsigned int* tgtbf = (unsigned int*)(p + SRCBF_B);
    float* invnw    = (float*)(p + SRCBF_B + TGTBF_B);
    float* cand_val = (float*)(p + SRCBF_B + TGTBF_B + INVN_B);
    int*   cand_idx = (int*)(p + SRCBF_B + TGTBF_B + INVN_B + CV_B);

    convert_src_kernel<<<256, 256, 0, stream>>>(src, srcbf);
    prep_tgt_kernel<<<N_TGT2 / 16, 256, 0, stream>>>(tgt, tgtbf, invnw);
    gemm_topk_fp8_kernel<<<NBLK, 512, 0, stream>>>(tgtbf, srcbf, invnw,
                                                   cand_val, cand_idx);
    merge_rerank_kernel<<<N_SRC, 256, 0, stream>>>(src, tgt,
                                                   cand_val, cand_idx, out);
}